// Round 1
// baseline (804.522 us; speedup 1.0000x reference)
//
#include <hip/hip_runtime.h>
#include <hip/hip_fp16.h>

#define NSEQ 8192
#define DIM  512

typedef _Float16 f16;
typedef _Float16 f16x8 __attribute__((ext_vector_type(8)));
typedef _Float16 f16x4 __attribute__((ext_vector_type(4)));
typedef float    f32x4 __attribute__((ext_vector_type(4)));

// ---------------------------------------------------------------------------
// Kernel 0a: C = X(8192x512) * W(512x512) in fp32 (vector ALU), epilogue
// splits each fp32 value into f16 hi + f16 lo (hi = f16(c), lo = f16(c-hi)).
// scale folds 1/sqrt(512) into Q.
// ---------------------------------------------------------------------------
__global__ __launch_bounds__(256) void k_proj_split(
    const float* __restrict__ X, const float* __restrict__ W,
    f16* __restrict__ Oh, f16* __restrict__ Ol, float scale)
{
  __shared__ float As[16][68];   // [k][row], padded to kill write conflicts
  __shared__ float Bs[16][64];   // [k][col]
  const int tid = threadIdx.x;
  const int r0 = blockIdx.x * 64;
  const int c0 = blockIdx.y * 64;
  const int tx = tid & 15, ty = tid >> 4;
  float acc[4][4] = {};
  for (int k0 = 0; k0 < DIM; k0 += 16) {
#pragma unroll
    for (int e = 0; e < 4; ++e) {
      int idx = tid + e * 256;
      As[idx & 15][idx >> 4] = X[(size_t)(r0 + (idx >> 4)) * DIM + k0 + (idx & 15)];
    }
#pragma unroll
    for (int e = 0; e < 4; ++e) {
      int idx = tid + e * 256;
      Bs[idx >> 6][idx & 63] = W[(size_t)(k0 + (idx >> 6)) * DIM + c0 + (idx & 63)];
    }
    __syncthreads();
#pragma unroll
    for (int kk = 0; kk < 16; ++kk) {
      f32x4 a = *(const f32x4*)&As[kk][ty * 4];
      f32x4 b = *(const f32x4*)&Bs[kk][tx * 4];
#pragma unroll
      for (int i = 0; i < 4; ++i)
#pragma unroll
        for (int j = 0; j < 4; ++j)
          acc[i][j] = fmaf(a[i], b[j], acc[i][j]);
    }
    __syncthreads();
  }
#pragma unroll
  for (int i = 0; i < 4; ++i) {
    f16x4 hv, lv;
#pragma unroll
    for (int j = 0; j < 4; ++j) {
      float c = acc[i][j] * scale;
      f16 h = (f16)c;
      hv[j] = h;
      lv[j] = (f16)(c - (float)h);
    }
    size_t addr = (size_t)(r0 + ty * 4 + i) * DIM + c0 + tx * 4;
    *(f16x4*)&Oh[addr] = hv;
    *(f16x4*)&Ol[addr] = lv;
  }
}

// ---------------------------------------------------------------------------
// Kernel 0b: XhT[d][j] = f16(X[j][d])  (transposed f16 copy of V for PV pass)
// ---------------------------------------------------------------------------
__global__ __launch_bounds__(256) void k_xt(const float* __restrict__ X,
                                            f16* __restrict__ XhT)
{
  __shared__ float T[64][65];
  const int tid = threadIdx.x;
  const int j0 = blockIdx.x * 64;   // seq
  const int d0 = blockIdx.y * 64;   // dim
#pragma unroll
  for (int e = 0; e < 16; ++e) {
    int idx = tid + e * 256;
    T[idx >> 6][idx & 63] = X[(size_t)(j0 + (idx >> 6)) * DIM + d0 + (idx & 63)];
  }
  __syncthreads();
#pragma unroll
  for (int e = 0; e < 16; ++e) {
    int idx = tid + e * 256;
    int dd = idx >> 6, jj = idx & 63;
    XhT[(size_t)(d0 + dd) * NSEQ + j0 + jj] = (f16)T[jj][dd];
  }
}

// ---------------------------------------------------------------------------
// Pass A: S = Q K^T via split-f16 MFMA (3 mfma per fragment pair).
// 128x128 block tile, 4 waves (64x64 each), BK=32, XOR-swizzled LDS.
// S rows are chunk-local (q0 = global row offset of chunk).
// ---------------------------------------------------------------------------
__global__ __launch_bounds__(256) void k_qkt(
    const f16* __restrict__ Qh, const f16* __restrict__ Ql,
    const f16* __restrict__ Kh, const f16* __restrict__ Kl,
    float* __restrict__ S, int q0)
{
  __shared__ char sm[4 * 8192];   // Qh,Ql,Kh,Kl tiles: [128][32] f16, 8 KB each
  const int tid  = threadIdx.x;
  const int lane = tid & 63;
  const int w    = tid >> 6;
  const int wm   = (w >> 1) * 64;
  const int wn   = (w & 1) * 64;
  const int qrow0 = q0 + blockIdx.x * 128;
  const int krow0 = blockIdx.y * 128;

  // staging: each thread stages rows r1 and r1+64 at 16B column chunk o1
  const int r1 = tid >> 2;
  const int o1 = (tid & 3) * 8;                       // f16 elems
  const int sw1 = (r1 * 64 + (tid & 3) * 16) ^ ((r1 & 7) << 4);
  const int sw2 = ((r1 + 64) * 64 + (tid & 3) * 16) ^ (((r1 + 64) & 7) << 4);
  const f16* pQh = Qh + (size_t)(qrow0 + r1) * DIM + o1;
  const f16* pQl = Ql + (size_t)(qrow0 + r1) * DIM + o1;
  const f16* pKh = Kh + (size_t)(krow0 + r1) * DIM + o1;
  const f16* pKl = Kl + (size_t)(krow0 + r1) * DIM + o1;
  const int R64 = 64 * DIM;

  const int frow = lane & 15;
  const int fkb  = (lane >> 4) * 16;

  f32x4 acc[4][4] = {};

  for (int step = 0; step < 16; ++step) {
    const int d0 = step * 32;
    uint4 v0 = *(const uint4*)(pQh + d0);
    uint4 v1 = *(const uint4*)(pQh + R64 + d0);
    uint4 v2 = *(const uint4*)(pQl + d0);
    uint4 v3 = *(const uint4*)(pQl + R64 + d0);
    uint4 v4 = *(const uint4*)(pKh + d0);
    uint4 v5 = *(const uint4*)(pKh + R64 + d0);
    uint4 v6 = *(const uint4*)(pKl + d0);
    uint4 v7 = *(const uint4*)(pKl + R64 + d0);
    __syncthreads();                       // prev-iter reads done
    *(uint4*)(sm +     0 + sw1) = v0;
    *(uint4*)(sm +     0 + sw2) = v1;
    *(uint4*)(sm +  8192 + sw1) = v2;
    *(uint4*)(sm +  8192 + sw2) = v3;
    *(uint4*)(sm + 16384 + sw1) = v4;
    *(uint4*)(sm + 16384 + sw2) = v5;
    *(uint4*)(sm + 24576 + sw1) = v6;
    *(uint4*)(sm + 24576 + sw2) = v7;
    __syncthreads();                       // publish
    f16x8 aH[4], aL[4], bH[4], bL[4];
#pragma unroll
    for (int m = 0; m < 4; ++m) {
      int ra = wm + m * 16 + frow;
      int rb = wn + m * 16 + frow;
      int sa = (ra * 64 + fkb) ^ ((ra & 7) << 4);
      int sb = (rb * 64 + fkb) ^ ((rb & 7) << 4);
      aH[m] = *(const f16x8*)(sm +     0 + sa);
      aL[m] = *(const f16x8*)(sm +  8192 + sa);
      bH[m] = *(const f16x8*)(sm + 16384 + sb);
      bL[m] = *(const f16x8*)(sm + 24576 + sb);
    }
#pragma unroll
    for (int m = 0; m < 4; ++m)
#pragma unroll
      for (int n = 0; n < 4; ++n) {
        acc[m][n] = __builtin_amdgcn_mfma_f32_16x16x32_f16(aH[m], bH[n], acc[m][n], 0, 0, 0);
        acc[m][n] = __builtin_amdgcn_mfma_f32_16x16x32_f16(aH[m], bL[n], acc[m][n], 0, 0, 0);
        acc[m][n] = __builtin_amdgcn_mfma_f32_16x16x32_f16(aL[m], bH[n], acc[m][n], 0, 0, 0);
      }
  }

  const int srow0 = blockIdx.x * 128 + wm;   // chunk-local S row
  const int scol0 = krow0 + wn;
#pragma unroll
  for (int m = 0; m < 4; ++m)
#pragma unroll
    for (int n = 0; n < 4; ++n) {
      int row = srow0 + m * 16 + (lane >> 4) * 4;
      int col = scol0 + n * 16 + (lane & 15);
#pragma unroll
      for (int r = 0; r < 4; ++r)
        S[(size_t)(row + r) * NSEQ + col] = acc[m][n][r];
    }
}

// ---------------------------------------------------------------------------
// Pass B: one block per row. Row max + sum(exp), writes P=f16(exp(s-m)) and
// the row sum. P may overlay the S buffer (ppitch in f16 elems).
// ---------------------------------------------------------------------------
__global__ __launch_bounds__(256) void k_softmax(
    const float* __restrict__ S, f16* __restrict__ P,
    float* __restrict__ Lsum, int q0, int ppitch)
{
  __shared__ float red[4], red2[4];
  const int tid = threadIdx.x;
  const int r = blockIdx.x;
  const float* srow = S + (size_t)r * NSEQ;
  f32x4 v[8];
#pragma unroll
  for (int e = 0; e < 8; ++e)
    v[e] = *(const f32x4*)(srow + (size_t)(tid + e * 256) * 4);
  float m = -3.0e38f;
#pragma unroll
  for (int e = 0; e < 8; ++e)
#pragma unroll
    for (int i = 0; i < 4; ++i) m = fmaxf(m, v[e][i]);
#pragma unroll
  for (int off = 32; off; off >>= 1) m = fmaxf(m, __shfl_xor(m, off));
  if ((tid & 63) == 0) red[tid >> 6] = m;
  __syncthreads();
  m = fmaxf(fmaxf(red[0], red[1]), fmaxf(red[2], red[3]));
  float sum = 0.f;
#pragma unroll
  for (int e = 0; e < 8; ++e)
#pragma unroll
    for (int i = 0; i < 4; ++i) {
      float p = __expf(v[e][i] - m);
      v[e][i] = p;
      sum += p;
    }
#pragma unroll
  for (int off = 32; off; off >>= 1) sum += __shfl_xor(sum, off);
  if ((tid & 63) == 0) red2[tid >> 6] = sum;
  __syncthreads();
  sum = red2[0] + red2[1] + red2[2] + red2[3];
  if (tid == 0) Lsum[q0 + r] = sum;
  f16* prow = P + (size_t)(q0 + r) * ppitch;
#pragma unroll
  for (int e = 0; e < 8; ++e) {
    f16x4 p;
#pragma unroll
    for (int i = 0; i < 4; ++i) p[i] = (f16)v[e][i];
    *(f16x4*)(prow + (size_t)(tid + e * 256) * 4) = p;
  }
}

// ---------------------------------------------------------------------------
// Pass C: O^T = XhT * P^T  (f16 MFMA, fp32 acc). Block tile: 128 d x 128 q,
// grid (4, 64) = 256 blocks. Epilogue: scale 1/l, LDS transpose, coalesced
// fp32 stores of O[q][d].
// ---------------------------------------------------------------------------
__global__ __launch_bounds__(256) void k_pv(
    const f16* __restrict__ XhT, const f16* __restrict__ P,
    const float* __restrict__ Lsum, float* __restrict__ Out, int ppitch)
{
  __shared__ float smO[64 * 132];          // 33792 B; also aliases sA/sB
  char* smb = (char*)smO;                  // sA at 0 (16 KB), sB at 16384 (16 KB)
  const int tid  = threadIdx.x;
  const int lane = tid & 63;
  const int w    = tid >> 6;
  const int wm   = (w >> 1) * 64;          // d offset in tile
  const int wn   = (w & 1) * 64;           // q offset in tile
  const int d0   = blockIdx.x * 128;
  const int qq0  = blockIdx.y * 128;

  const int jo   = (tid & 7) * 8;          // f16 elems within 64-wide j slice
  const int row0 = tid >> 3;               // 0..31, +32 per e
  int swA[4];
#pragma unroll
  for (int e = 0; e < 4; ++e) {
    int row = row0 + e * 32;
    swA[e] = (row * 128 + (tid & 7) * 16) ^ ((row & 7) << 4);
  }
  const f16* pA = XhT + (size_t)(d0 + row0) * NSEQ + jo;
  const f16* pB = P + (size_t)(qq0 + row0) * ppitch + jo;
  const int strideA = 32 * NSEQ;
  const int strideB = 32 * ppitch;
  const int frow = lane & 15;

  f32x4 acc[4][4] = {};
  for (int step = 0; step < 128; ++step) {
    const int j0 = step * 64;
    uint4 va[4], vb[4];
#pragma unroll
    for (int e = 0; e < 4; ++e) {
      va[e] = *(const uint4*)(pA + (size_t)e * strideA + j0);
      vb[e] = *(const uint4*)(pB + (size_t)e * strideB + j0);
    }
    __syncthreads();
#pragma unroll
    for (int e = 0; e < 4; ++e) {
      *(uint4*)(smb +     0 + swA[e]) = va[e];
      *(uint4*)(smb + 16384 + swA[e]) = vb[e];
    }
    __syncthreads();
#pragma unroll
    for (int kk = 0; kk < 2; ++kk) {
      const int fkb = kk * 64 + (lane >> 4) * 16;
      f16x8 a[4], b[4];
#pragma unroll
      for (int m = 0; m < 4; ++m) {
        int ra = wm + m * 16 + frow;
        int rb = wn + m * 16 + frow;
        a[m] = *(const f16x8*)(smb +     0 + ((ra * 128 + fkb) ^ ((ra & 7) << 4)));
        b[m] = *(const f16x8*)(smb + 16384 + ((rb * 128 + fkb) ^ ((rb & 7) << 4)));
      }
#pragma unroll
      for (int m = 0; m < 4; ++m)
#pragma unroll
        for (int n = 0; n < 4; ++n)
          acc[m][n] = __builtin_amdgcn_mfma_f32_16x16x32_f16(a[m], b[n], acc[m][n], 0, 0, 0);
    }
  }

  float linv[4];
#pragma unroll
  for (int n = 0; n < 4; ++n)
    linv[n] = 1.0f / Lsum[qq0 + wn + n * 16 + (lane & 15)];

  __syncthreads();   // all frag reads done before smO reuse
#pragma unroll
  for (int ph = 0; ph < 2; ++ph) {
    if ((w & 1) == ph) {
#pragma unroll
      for (int m = 0; m < 4; ++m)
#pragma unroll
        for (int n = 0; n < 4; ++n) {
          int qq = n * 16 + (lane & 15);
          int dd = wm + m * 16 + (lane >> 4) * 4;
#pragma unroll
          for (int r = 0; r < 4; ++r)
            smO[qq * 132 + dd + r] = acc[m][n][r] * linv[n];
        }
    }
    __syncthreads();
#pragma unroll
    for (int e = 0; e < 8; ++e) {
      int idx = tid + e * 256;
      int row = idx >> 5, c4 = idx & 31;
      f32x4 vv = *(const f32x4*)&smO[row * 132 + c4 * 4];
      *(f32x4*)(Out + (size_t)(qq0 + ph * 64 + row) * DIM + d0 + c4 * 4) = vv;
    }
    __syncthreads();
  }
}

// ---------------------------------------------------------------------------
extern "C" void kernel_launch(void* const* d_in, const int* in_sizes, int n_in,
                              void* d_out, int out_size, void* d_ws, size_t ws_size,
                              hipStream_t stream) {
  const float* Wq = (const float*)d_in[0];   // rotation_params
  const float* Wk = (const float*)d_in[1];   // entangle_params
  const float* X  = (const float*)d_in[2];   // inputs
  float* Out = (float*)d_out;

  char* w = (char*)d_ws;
  const size_t SPLIT = (size_t)NSEQ * DIM * 2;           // 8 MB per f16 matrix
  f16*   Qh   = (f16*)(w);
  f16*   Ql   = (f16*)(w + SPLIT);
  f16*   Kh   = (f16*)(w + 2 * SPLIT);
  f16*   Kl   = (f16*)(w + 3 * SPLIT);
  f16*   XhT  = (f16*)(w + 4 * SPLIT);
  float* Lsum = (float*)(w + 5 * SPLIT);
  const size_t used_base = 5 * SPLIT + 32768;
  char* rest = w + used_base;
  const size_t SBYTES_FULL = (size_t)NSEQ * NSEQ * 4;    // 256 MB
  const size_t PBYTES      = (size_t)NSEQ * NSEQ * 2;    // 128 MB

  float* S; f16* P; int ppitch; int CQ;
  if (ws_size >= used_base + SBYTES_FULL) {
    // Full S; P (f16) overlays the first half of each 32 KB S row.
    S = (float*)rest; P = (f16*)rest; ppitch = 2 * NSEQ; CQ = NSEQ;
  } else {
    // Separate P, chunked S sized to the workspace.
    P = (f16*)rest; ppitch = NSEQ;
    S = (float*)(rest + PBYTES);
    size_t avail = (ws_size > used_base + PBYTES) ? ws_size - used_base - PBYTES : 0;
    CQ = 4096;
    while (CQ > 128 && (size_t)CQ * NSEQ * 4 > avail) CQ >>= 1;
  }

  const float SCALE = 0.044194173824159216f;  // 1/sqrt(512)
  k_proj_split<<<dim3(NSEQ / 64, DIM / 64), 256, 0, stream>>>(X, Wq, Qh, Ql, SCALE);
  k_proj_split<<<dim3(NSEQ / 64, DIM / 64), 256, 0, stream>>>(X, Wk, Kh, Kl, 1.0f);
  k_xt<<<dim3(NSEQ / 64, DIM / 64), 256, 0, stream>>>(X, XhT);
  for (int q0 = 0; q0 < NSEQ; q0 += CQ) {
    k_qkt<<<dim3(CQ / 128, NSEQ / 128), 256, 0, stream>>>(Qh, Ql, Kh, Kl, S, q0);
    k_softmax<<<dim3(CQ), 256, 0, stream>>>(S, P, Lsum, q0, ppitch);
  }
  k_pv<<<dim3(DIM / 128, NSEQ / 128), 256, 0, stream>>>(XhT, P, Lsum, Out, ppitch);
}

// Round 2
// 803.006 us; speedup vs baseline: 1.0019x; 1.0019x over previous
//
#include <hip/hip_runtime.h>
#include <hip/hip_fp16.h>

#define NSEQ 8192
#define DIM  512

typedef _Float16 f16;
typedef _Float16 f16x8 __attribute__((ext_vector_type(8)));
typedef _Float16 f16x4 __attribute__((ext_vector_type(4)));
typedef float    f32x4 __attribute__((ext_vector_type(4)));

// ---------------------------------------------------------------------------
// Kernel 0a: C = X(8192x512) * W(512x512) in fp32 (vector ALU), epilogue
// splits each fp32 value into f16 hi + f16 lo (hi = f16(c), lo = f16(c-hi)).
// scale folds 1/sqrt(512) into Q.
// ---------------------------------------------------------------------------
__global__ __launch_bounds__(256) void k_proj_split(
    const float* __restrict__ X, const float* __restrict__ W,
    f16* __restrict__ Oh, f16* __restrict__ Ol, float scale)
{
  __shared__ float As[16][68];   // [k][row], padded to kill write conflicts
  __shared__ float Bs[16][64];   // [k][col]
  const int tid = threadIdx.x;
  const int r0 = blockIdx.x * 64;
  const int c0 = blockIdx.y * 64;
  const int tx = tid & 15, ty = tid >> 4;
  float acc[4][4] = {};
  for (int k0 = 0; k0 < DIM; k0 += 16) {
#pragma unroll
    for (int e = 0; e < 4; ++e) {
      int idx = tid + e * 256;
      As[idx & 15][idx >> 4] = X[(size_t)(r0 + (idx >> 4)) * DIM + k0 + (idx & 15)];
    }
#pragma unroll
    for (int e = 0; e < 4; ++e) {
      int idx = tid + e * 256;
      Bs[idx >> 6][idx & 63] = W[(size_t)(k0 + (idx >> 6)) * DIM + c0 + (idx & 63)];
    }
    __syncthreads();
#pragma unroll
    for (int kk = 0; kk < 16; ++kk) {
      f32x4 a = *(const f32x4*)&As[kk][ty * 4];
      f32x4 b = *(const f32x4*)&Bs[kk][tx * 4];
#pragma unroll
      for (int i = 0; i < 4; ++i)
#pragma unroll
        for (int j = 0; j < 4; ++j)
          acc[i][j] = fmaf(a[i], b[j], acc[i][j]);
    }
    __syncthreads();
  }
#pragma unroll
  for (int i = 0; i < 4; ++i) {
    f16x4 hv, lv;
#pragma unroll
    for (int j = 0; j < 4; ++j) {
      float c = acc[i][j] * scale;
      f16 h = (f16)c;
      hv[j] = h;
      lv[j] = (f16)(c - (float)h);
    }
    size_t addr = (size_t)(r0 + ty * 4 + i) * DIM + c0 + tx * 4;
    *(f16x4*)&Oh[addr] = hv;
    *(f16x4*)&Ol[addr] = lv;
  }
}

// ---------------------------------------------------------------------------
// Kernel 0b: XhT[d][j] = f16(X[j][d])  (transposed f16 copy of V for PV pass)
// ---------------------------------------------------------------------------
__global__ __launch_bounds__(256) void k_xt(const float* __restrict__ X,
                                            f16* __restrict__ XhT)
{
  __shared__ float T[64][65];
  const int tid = threadIdx.x;
  const int j0 = blockIdx.x * 64;   // seq
  const int d0 = blockIdx.y * 64;   // dim
#pragma unroll
  for (int e = 0; e < 16; ++e) {
    int idx = tid + e * 256;
    T[idx >> 6][idx & 63] = X[(size_t)(j0 + (idx >> 6)) * DIM + d0 + (idx & 63)];
  }
  __syncthreads();
#pragma unroll
  for (int e = 0; e < 16; ++e) {
    int idx = tid + e * 256;
    int dd = idx >> 6, jj = idx & 63;
    XhT[(size_t)(d0 + dd) * NSEQ + j0 + jj] = (f16)T[jj][dd];
  }
}

// ---------------------------------------------------------------------------
// Pass A: S = Q K^T via split-f16 MFMA (3 mfma per fragment pair).
// 128x128 block tile, 4 waves (64x64 each), BK=32, XOR-swizzled LDS.
// S rows are chunk-local (q0 = global row offset of chunk).
// ---------------------------------------------------------------------------
__global__ __launch_bounds__(256) void k_qkt(
    const f16* __restrict__ Qh, const f16* __restrict__ Ql,
    const f16* __restrict__ Kh, const f16* __restrict__ Kl,
    float* __restrict__ S, int q0)
{
  __shared__ char sm[4 * 8192];   // Qh,Ql,Kh,Kl tiles: [128][32] f16, 8 KB each
  const int tid  = threadIdx.x;
  const int lane = tid & 63;
  const int w    = tid >> 6;
  const int wm   = (w >> 1) * 64;
  const int wn   = (w & 1) * 64;
  const int qrow0 = q0 + blockIdx.x * 128;
  const int krow0 = blockIdx.y * 128;

  // staging: each thread stages rows r1 and r1+64 at 16B column chunk o1
  const int r1 = tid >> 2;
  const int o1 = (tid & 3) * 8;                       // f16 elems
  const int sw1 = (r1 * 64 + (tid & 3) * 16) ^ ((r1 & 7) << 4);
  const int sw2 = ((r1 + 64) * 64 + (tid & 3) * 16) ^ (((r1 + 64) & 7) << 4);
  const f16* pQh = Qh + (size_t)(qrow0 + r1) * DIM + o1;
  const f16* pQl = Ql + (size_t)(qrow0 + r1) * DIM + o1;
  const f16* pKh = Kh + (size_t)(krow0 + r1) * DIM + o1;
  const f16* pKl = Kl + (size_t)(krow0 + r1) * DIM + o1;
  const int R64 = 64 * DIM;

  const int frow = lane & 15;
  const int fkb  = (lane >> 4) * 16;

  f32x4 acc[4][4] = {};

  for (int step = 0; step < 16; ++step) {
    const int d0 = step * 32;
    uint4 v0 = *(const uint4*)(pQh + d0);
    uint4 v1 = *(const uint4*)(pQh + R64 + d0);
    uint4 v2 = *(const uint4*)(pQl + d0);
    uint4 v3 = *(const uint4*)(pQl + R64 + d0);
    uint4 v4 = *(const uint4*)(pKh + d0);
    uint4 v5 = *(const uint4*)(pKh + R64 + d0);
    uint4 v6 = *(const uint4*)(pKl + d0);
    uint4 v7 = *(const uint4*)(pKl + R64 + d0);
    __syncthreads();                       // prev-iter reads done
    *(uint4*)(sm +     0 + sw1) = v0;
    *(uint4*)(sm +     0 + sw2) = v1;
    *(uint4*)(sm +  8192 + sw1) = v2;
    *(uint4*)(sm +  8192 + sw2) = v3;
    *(uint4*)(sm + 16384 + sw1) = v4;
    *(uint4*)(sm + 16384 + sw2) = v5;
    *(uint4*)(sm + 24576 + sw1) = v6;
    *(uint4*)(sm + 24576 + sw2) = v7;
    __syncthreads();                       // publish
    f16x8 aH[4], aL[4], bH[4], bL[4];
#pragma unroll
    for (int m = 0; m < 4; ++m) {
      int ra = wm + m * 16 + frow;
      int rb = wn + m * 16 + frow;
      int sa = (ra * 64 + fkb) ^ ((ra & 7) << 4);
      int sb = (rb * 64 + fkb) ^ ((rb & 7) << 4);
      aH[m] = *(const f16x8*)(sm +     0 + sa);
      aL[m] = *(const f16x8*)(sm +  8192 + sa);
      bH[m] = *(const f16x8*)(sm + 16384 + sb);
      bL[m] = *(const f16x8*)(sm + 24576 + sb);
    }
#pragma unroll
    for (int m = 0; m < 4; ++m)
#pragma unroll
      for (int n = 0; n < 4; ++n) {
        acc[m][n] = __builtin_amdgcn_mfma_f32_16x16x32_f16(aH[m], bH[n], acc[m][n], 0, 0, 0);
        acc[m][n] = __builtin_amdgcn_mfma_f32_16x16x32_f16(aH[m], bL[n], acc[m][n], 0, 0, 0);
        acc[m][n] = __builtin_amdgcn_mfma_f32_16x16x32_f16(aL[m], bH[n], acc[m][n], 0, 0, 0);
      }
  }

  const int srow0 = blockIdx.x * 128 + wm;   // chunk-local S row
  const int scol0 = krow0 + wn;
#pragma unroll
  for (int m = 0; m < 4; ++m)
#pragma unroll
    for (int n = 0; n < 4; ++n) {
      int row = srow0 + m * 16 + (lane >> 4) * 4;
      int col = scol0 + n * 16 + (lane & 15);
#pragma unroll
      for (int r = 0; r < 4; ++r)
        S[(size_t)(row + r) * NSEQ + col] = acc[m][n][r];
    }
}

// ---------------------------------------------------------------------------
// Pass B: one block per row. Row max + sum(exp), writes P=f16(exp(s-m)) and
// the row sum. P may overlay the S buffer (ppitch in f16 elems).
// ---------------------------------------------------------------------------
__global__ __launch_bounds__(256) void k_softmax(
    const float* __restrict__ S, f16* __restrict__ P,
    float* __restrict__ Lsum, int q0, int ppitch)
{
  __shared__ float red[4], red2[4];
  const int tid = threadIdx.x;
  const int r = blockIdx.x;
  const float* srow = S + (size_t)r * NSEQ;
  f32x4 v[8];
#pragma unroll
  for (int e = 0; e < 8; ++e)
    v[e] = *(const f32x4*)(srow + (size_t)(tid + e * 256) * 4);
  float m = -3.0e38f;
#pragma unroll
  for (int e = 0; e < 8; ++e)
#pragma unroll
    for (int i = 0; i < 4; ++i) m = fmaxf(m, v[e][i]);
#pragma unroll
  for (int off = 32; off; off >>= 1) m = fmaxf(m, __shfl_xor(m, off));
  if ((tid & 63) == 0) red[tid >> 6] = m;
  __syncthreads();
  m = fmaxf(fmaxf(red[0], red[1]), fmaxf(red[2], red[3]));
  float sum = 0.f;
#pragma unroll
  for (int e = 0; e < 8; ++e)
#pragma unroll
    for (int i = 0; i < 4; ++i) {
      float p = __expf(v[e][i] - m);
      v[e][i] = p;
      sum += p;
    }
#pragma unroll
  for (int off = 32; off; off >>= 1) sum += __shfl_xor(sum, off);
  if ((tid & 63) == 0) red2[tid >> 6] = sum;
  __syncthreads();
  sum = red2[0] + red2[1] + red2[2] + red2[3];
  if (tid == 0) Lsum[q0 + r] = sum;
  f16* prow = P + (size_t)(q0 + r) * ppitch;
#pragma unroll
  for (int e = 0; e < 8; ++e) {
    f16x4 p;
#pragma unroll
    for (int i = 0; i < 4; ++i) p[i] = (f16)v[e][i];
    *(f16x4*)(prow + (size_t)(tid + e * 256) * 4) = p;
  }
}

// ---------------------------------------------------------------------------
// Pass C: Opart^T = XhT * P^T over a K-slice (split-K).  f16 MFMA, fp32 acc.
// Block tile: 128 d x 128 q; grid (4, 64, KSPLIT).  Each z-slice handles
// NSEQ/KSPLIT of the j dimension and writes an UNSCALED partial O tile
// (fp32, [q][d] layout) at obase + q*qstride + z*kpstride + d*4.
// ---------------------------------------------------------------------------
__global__ __launch_bounds__(256) void k_pv(
    const f16* __restrict__ XhT, const f16* __restrict__ P,
    char* __restrict__ obase, int ppitch, size_t qstride, size_t kpstride)
{
  __shared__ float smO[64 * 132];          // 33792 B; also aliases sA/sB
  char* smb = (char*)smO;                  // sA at 0 (16 KB), sB at 16384 (16 KB)
  const int tid  = threadIdx.x;
  const int lane = tid & 63;
  const int w    = tid >> 6;
  const int wm   = (w >> 1) * 64;          // d offset in tile
  const int wn   = (w & 1) * 64;           // q offset in tile
  const int d0   = blockIdx.x * 128;
  const int qq0  = blockIdx.y * 128;
  const int kz   = blockIdx.z;
  const int ksteps = (NSEQ / 64) / gridDim.z;
  const int kbase  = kz * ksteps;

  const int jo   = (tid & 7) * 8;          // f16 elems within 64-wide j slice
  const int row0 = tid >> 3;               // 0..31, +32 per e
  int swA[4];
#pragma unroll
  for (int e = 0; e < 4; ++e) {
    int row = row0 + e * 32;
    swA[e] = (row * 128 + (tid & 7) * 16) ^ ((row & 7) << 4);
  }
  const f16* pA = XhT + (size_t)(d0 + row0) * NSEQ + jo;
  const f16* pB = P + (size_t)(qq0 + row0) * ppitch + jo;
  const int strideA = 32 * NSEQ;
  const int strideB = 32 * ppitch;
  const int frow = lane & 15;

  f32x4 acc[4][4] = {};
  for (int step = 0; step < ksteps; ++step) {
    const int j0 = (kbase + step) * 64;
    uint4 va[4], vb[4];
#pragma unroll
    for (int e = 0; e < 4; ++e) {
      va[e] = *(const uint4*)(pA + (size_t)e * strideA + j0);
      vb[e] = *(const uint4*)(pB + (size_t)e * strideB + j0);
    }
    __syncthreads();
#pragma unroll
    for (int e = 0; e < 4; ++e) {
      *(uint4*)(smb +     0 + swA[e]) = va[e];
      *(uint4*)(smb + 16384 + swA[e]) = vb[e];
    }
    __syncthreads();
#pragma unroll
    for (int kk = 0; kk < 2; ++kk) {
      const int fkb = kk * 64 + (lane >> 4) * 16;
      f16x8 a[4], b[4];
#pragma unroll
      for (int m = 0; m < 4; ++m) {
        int ra = wm + m * 16 + frow;
        int rb = wn + m * 16 + frow;
        a[m] = *(const f16x8*)(smb +     0 + ((ra * 128 + fkb) ^ ((ra & 7) << 4)));
        b[m] = *(const f16x8*)(smb + 16384 + ((rb * 128 + fkb) ^ ((rb & 7) << 4)));
      }
#pragma unroll
      for (int m = 0; m < 4; ++m)
#pragma unroll
        for (int n = 0; n < 4; ++n)
          acc[m][n] = __builtin_amdgcn_mfma_f32_16x16x32_f16(a[m], b[n], acc[m][n], 0, 0, 0);
    }
  }

  __syncthreads();   // all frag reads done before smO reuse
#pragma unroll
  for (int ph = 0; ph < 2; ++ph) {
    if ((w & 1) == ph) {
#pragma unroll
      for (int m = 0; m < 4; ++m)
#pragma unroll
        for (int n = 0; n < 4; ++n) {
          int qq = n * 16 + (lane & 15);
          int dd = wm + m * 16 + (lane >> 4) * 4;
#pragma unroll
          for (int r = 0; r < 4; ++r)
            smO[qq * 132 + dd + r] = acc[m][n][r];
        }
    }
    __syncthreads();
#pragma unroll
    for (int e = 0; e < 8; ++e) {
      int idx = tid + e * 256;
      int row = idx >> 5, c4 = idx & 31;
      f32x4 vv = *(const f32x4*)&smO[row * 132 + c4 * 4];
      *(f32x4*)(obase + (size_t)(qq0 + ph * 64 + row) * qstride
                      + (size_t)kz * kpstride + (size_t)(d0 + c4 * 4) * 4) = vv;
    }
    __syncthreads();
  }
}

// ---------------------------------------------------------------------------
// Pass D: Out[q][d] = (sum_kp Opart[kp][q][d]) / Lsum[q].
// One f32x4 per thread; grid covers 8192 x 512.
// Works in-place when obase==Out (ksplit==1, kpstride==0).
// ---------------------------------------------------------------------------
__global__ __launch_bounds__(256) void k_reduce(
    const char* __restrict__ obase, size_t qstride, size_t kpstride, int ksplit,
    const float* __restrict__ Lsum, float* __restrict__ Out)
{
  const int idx = blockIdx.x * 256 + threadIdx.x;   // one f32x4
  const int q = idx >> 7;            // 128 vec4 per row (512 d)
  const int d4 = idx & 127;
  const char* p = obase + (size_t)q * qstride + (size_t)d4 * 16;
  f32x4 s = *(const f32x4*)p;
  for (int kp = 1; kp < ksplit; ++kp)
    s += *(const f32x4*)(p + (size_t)kp * kpstride);
  float linv = 1.0f / Lsum[q];
  s *= linv;
  *(f32x4*)(Out + (size_t)q * DIM + d4 * 4) = s;
}

// ---------------------------------------------------------------------------
extern "C" void kernel_launch(void* const* d_in, const int* in_sizes, int n_in,
                              void* d_out, int out_size, void* d_ws, size_t ws_size,
                              hipStream_t stream) {
  const float* Wq = (const float*)d_in[0];   // rotation_params
  const float* Wk = (const float*)d_in[1];   // entangle_params
  const float* X  = (const float*)d_in[2];   // inputs
  float* Out = (float*)d_out;

  char* w = (char*)d_ws;
  const size_t SPLIT = (size_t)NSEQ * DIM * 2;           // 8 MB per f16 matrix
  f16*   Qh   = (f16*)(w);
  f16*   Ql   = (f16*)(w + SPLIT);
  f16*   Kh   = (f16*)(w + 2 * SPLIT);
  f16*   Kl   = (f16*)(w + 3 * SPLIT);
  f16*   XhT  = (f16*)(w + 4 * SPLIT);
  float* Lsum = (float*)(w + 5 * SPLIT);
  const size_t used_base = 5 * SPLIT + 32768;
  char* rest = w + used_base;
  const size_t SBYTES_FULL = (size_t)NSEQ * NSEQ * 4;    // 256 MB
  const size_t PBYTES      = (size_t)NSEQ * NSEQ * 2;    // 128 MB
  const size_t OPART1      = (size_t)NSEQ * DIM * 4;     // 16 MB per partial

  float* S; f16* P; int ppitch; int CQ;
  int KSPLIT; char* obase; size_t qstride, kpstride;
  if (ws_size >= used_base + SBYTES_FULL) {
    // Full S; P (f16) overlays the first 16 KB of each 32 KB S row; the
    // dead upper 16 KB of each row holds the 8 split-K partials (8 x 2 KB).
    S = (float*)rest; P = (f16*)rest; ppitch = 2 * NSEQ; CQ = NSEQ;
    KSPLIT = 8;
    obase = rest + 16384;          // upper half of row 0
    qstride = 32768;               // one S row
    kpstride = 2048;               // 512 fp32 per partial row
  } else {
    // Separate P, chunked S sized to the workspace. After the last softmax
    // chunk the S region is dead -> holds the split-K partials.
    P = (f16*)rest; ppitch = NSEQ;
    S = (float*)(rest + PBYTES);
    size_t avail = (ws_size > used_base + PBYTES) ? ws_size - used_base - PBYTES : 0;
    CQ = 4096;
    while (CQ > 128 && (size_t)CQ * NSEQ * 4 > avail) CQ >>= 1;
    size_t schunk = (size_t)CQ * NSEQ * 4;
    KSPLIT = (int)(schunk / OPART1);
    if (KSPLIT > 8) KSPLIT = 8;
    if (KSPLIT >= 1) {
      obase = (char*)S; qstride = DIM * 4; kpstride = OPART1;
    } else {
      // No room for even one partial: write unscaled O directly to d_out,
      // k_reduce then scales in place.
      KSPLIT = 1; obase = (char*)Out; qstride = DIM * 4; kpstride = 0;
    }
  }

  const float SCALE = 0.044194173824159216f;  // 1/sqrt(512)
  k_proj_split<<<dim3(NSEQ / 64, DIM / 64), 256, 0, stream>>>(X, Wq, Qh, Ql, SCALE);
  k_proj_split<<<dim3(NSEQ / 64, DIM / 64), 256, 0, stream>>>(X, Wk, Kh, Kl, 1.0f);
  k_xt<<<dim3(NSEQ / 64, DIM / 64), 256, 0, stream>>>(X, XhT);
  for (int q0 = 0; q0 < NSEQ; q0 += CQ) {
    k_qkt<<<dim3(CQ / 128, NSEQ / 128), 256, 0, stream>>>(Qh, Ql, Kh, Kl, S, q0);
    k_softmax<<<dim3(CQ), 256, 0, stream>>>(S, P, Lsum, q0, ppitch);
  }
  k_pv<<<dim3(DIM / 128, NSEQ / 128, KSPLIT), 256, 0, stream>>>(XhT, P, obase, ppitch, qstride, kpstride);
  k_reduce<<<NSEQ * (DIM / 4) / 256, 256, 0, stream>>>(obase, qstride, kpstride, KSPLIT, Lsum, Out);
}